// Round 13
// baseline (479.591 us; speedup 1.0000x reference)
//
#include <hip/hip_runtime.h>

typedef _Float16 f16;
typedef __attribute__((ext_vector_type(8))) _Float16 f16x8;
typedef __attribute__((ext_vector_type(4))) float f32x4;

#define SEQ   4096
#define NH    16
#define HD    80
#define HIDN  1280
#define DP    96

// attn LDS geometry (R8-proven)
#define KSZ   3328          // 32 rows x 104 (padded) f16
#define VSZ   4480          // 80 rows x 56 (padded) f16
#define HSZ   (2*KSZ + 2*VSZ)   // one double-buffer half: 15616 f16 = 31,232 B

// 8-phase GEMM constants (QKV: M=4096, N=3840, K=1280), BK=32, 2 tiles/iter
#define KQ   1280
#define NQ   3840
#define NIT  20      // K / 64

__device__ __forceinline__ void gload16(const void* g, void* l) {
  __builtin_amdgcn_global_load_lds(
      (const __attribute__((address_space(1))) unsigned int*)g,
      (__attribute__((address_space(3))) unsigned int*)l, 16, 0, 0);
}

__device__ __forceinline__ unsigned pk2(float a, float b) {
  return __builtin_bit_cast(unsigned, __builtin_amdgcn_cvt_pkrtz(a, b));
}
__device__ __forceinline__ f16x8 bc16(uint4 u) { return __builtin_bit_cast(f16x8, u); }

#define BAR() __builtin_amdgcn_s_barrier()
#define VMCNT(n) do { asm volatile("s_waitcnt vmcnt(" #n ")" ::: "memory"); \
                      __builtin_amdgcn_sched_barrier(0); } while (0)
// stage one half-tile (128 rows x 32 K) = 1 gload_lds per thread
#define STG32(Lb, g, buf, h, kt)                                                \
  gload16((g) + (size_t)((h) * 128) * KQ + (kt) * 32,                           \
          (Lb) + (buf) * 8192 + (h) * 4096 + w * 512)
#define MFQ32(IOFF, JOFF, BB)                                                   \
  do {                                                                          \
    __builtin_amdgcn_s_setprio(1);                                              \
    _Pragma("unroll")                                                           \
    for (int i_ = 0; i_ < 4; i_++)                                              \
      _Pragma("unroll")                                                         \
      for (int j_ = 0; j_ < 2; j_++)                                            \
        acc[i_ + IOFF][j_ + JOFF] = __builtin_amdgcn_mfma_f32_16x16x32_f16(     \
            a[i_], BB[j_], acc[i_ + IOFF][j_ + JOFF], 0, 0, 0);                 \
    __builtin_amdgcn_s_setprio(0);                                              \
  } while (0)

// ---------------- fused f32 -> f16 convert for x, qkv_w, proj_w ----------------
__global__ __launch_bounds__(256) void cvt3_kernel(const float* __restrict__ s0,
                                                   const float* __restrict__ s1,
                                                   const float* __restrict__ s2,
                                                   f16* __restrict__ d0,
                                                   f16* __restrict__ d1,
                                                   f16* __restrict__ d2,
                                                   int n0, int n1, int n2) {
  long i = (long)(blockIdx.x * 256 + threadIdx.x) * 8;
  const float* s; f16* d;
  if (i < n0)                { s = s0 + i;            d = d0 + i; }
  else if (i < n0 + n1)      { s = s1 + (i - n0);     d = d1 + (i - n0); }
  else if (i < n0 + n1 + n2) { s = s2 + (i - n0 - n1); d = d2 + (i - n0 - n1); }
  else return;
  f32x4 v0 = *(const f32x4*)(s);
  f32x4 v1 = *(const f32x4*)(s + 4);
  f16x8 o;
#pragma unroll
  for (int j = 0; j < 4; j++) { o[j] = (f16)v0[j]; o[4 + j] = (f16)v1[j]; }
  *(f16x8*)(d) = o;
}

// ---------------- 8-phase 256^2 GEMM, BK=32, 64 KB LDS -> 2 blocks/CU ----------
// Same schedule shape as the proven BK=64 template; half-tiles are 1 gload each,
// VMCNT(2) = 2 half-tiles in flight. Swizzle key (row>>1)&3 over 4 k-chunks
// (covers 32 banks 2-way, free). Co-resident blocks hide barrier/fill stalls.
__global__ __launch_bounds__(512, 4) void qkv_gemm8(const f16* __restrict__ A,
                                                    const f16* __restrict__ B,
                                                    const float* __restrict__ bias,
                                                    f16* __restrict__ C) {
  __shared__ __align__(16) f16 LA[2 * 8192];
  __shared__ __align__(16) f16 LB[2 * 8192];
  const int tid = threadIdx.x, w = tid >> 6, l = tid & 63;
  const int bid = (blockIdx.x & 7) * 30 + (blockIdx.x >> 3);  // XCD swizzle, 240 = 8*30
  const int bx = bid % 15, by = bid / 15;
  const int m0 = by * 256, n0 = bx * 256;
  const int wm = (w >> 2) * 128, wn = (w & 3) * 64;
  const int fr = l & 15, fq = l >> 4;
  const int cA = (fq ^ ((fr >> 1) & 3)) * 8;   // swizzled k-chunk (read side)

  // staging source: chunk c = tid -> row c>>2, k-chunk (c&3) ^ ((c>>3)&3)
  const int srow = tid >> 2;
  const int scol = ((tid & 3) ^ ((tid >> 3) & 3)) * 8;
  const f16* gA = A + (size_t)(m0 + srow) * KQ + scol;
  const f16* gB = B + (size_t)(n0 + srow) * KQ + scol;

  f32x4 acc[8][4] = {};
  f16x8 a[4], b0[2], b1[2];

  // prologue: A,B of tile0 -> buf0; B of tile1 -> buf1
  STG32(LA, gA, 0, 0, 0); STG32(LA, gA, 0, 1, 0);
  STG32(LB, gB, 0, 0, 0); STG32(LB, gB, 0, 1, 0);
  STG32(LB, gB, 1, 0, 1); STG32(LB, gB, 1, 1, 1);
  VMCNT(2);
  BAR();

  for (int it = 0; it < NIT; ++it) {
    const int t = 2 * it;
    const bool lastit = (it == NIT - 1);

    // phase 1: ds aL,b0 (buf0) | stage A(t+1) h0 -> buf1 | MFMA q(0,0)
#pragma unroll
    for (int i = 0; i < 4; i++)
      a[i] = *(const f16x8*)(LA + (wm + i * 16 + fr) * 32 + cA);
#pragma unroll
    for (int j = 0; j < 2; j++)
      b0[j] = *(const f16x8*)(LB + (wn + j * 16 + fr) * 32 + cA);
    STG32(LA, gA, 1, 0, t + 1);
    BAR(); MFQ32(0, 0, b0); BAR();

    // phase 2: ds b1 (buf0) | stage A(t+1) h1 | MFMA q(0,2)
#pragma unroll
    for (int j = 0; j < 2; j++)
      b1[j] = *(const f16x8*)(LB + (wn + 32 + j * 16 + fr) * 32 + cA);
    STG32(LA, gA, 1, 1, t + 1);
    BAR(); MFQ32(0, 2, b1); BAR();

    // phase 3: ds aH (buf0) | stage B(t+2) h0 -> buf0 | MFMA q(4,0)
#pragma unroll
    for (int i = 0; i < 4; i++)
      a[i] = *(const f16x8*)(LA + (wm + 64 + i * 16 + fr) * 32 + cA);
    if (!lastit) { STG32(LB, gB, 0, 0, t + 2); }
    BAR(); MFQ32(4, 0, b0); BAR();

    // phase 4: stage B(t+2) h1 | vmcnt guard for buf1 | MFMA q(4,2)
    if (!lastit) { STG32(LB, gB, 0, 1, t + 2); VMCNT(2); }
    else         { VMCNT(0); }
    BAR(); MFQ32(4, 2, b1); BAR();

    // phase 5: ds aL,b0 (buf1) | stage A(t+2) h0 -> buf0 | MFMA q(0,0)
#pragma unroll
    for (int i = 0; i < 4; i++)
      a[i] = *(const f16x8*)(LA + 8192 + (wm + i * 16 + fr) * 32 + cA);
#pragma unroll
    for (int j = 0; j < 2; j++)
      b0[j] = *(const f16x8*)(LB + 8192 + (wn + j * 16 + fr) * 32 + cA);
    if (!lastit) { STG32(LA, gA, 0, 0, t + 2); }
    BAR(); MFQ32(0, 0, b0); BAR();

    // phase 6: ds b1 (buf1) | stage A(t+2) h1 | MFMA q(0,2)
#pragma unroll
    for (int j = 0; j < 2; j++)
      b1[j] = *(const f16x8*)(LB + 8192 + (wn + 32 + j * 16 + fr) * 32 + cA);
    if (!lastit) { STG32(LA, gA, 0, 1, t + 2); }
    BAR(); MFQ32(0, 2, b1); BAR();

    // phase 7: ds aH (buf1) | stage B(t+3) h0 -> buf1 | MFMA q(4,0)
#pragma unroll
    for (int i = 0; i < 4; i++)
      a[i] = *(const f16x8*)(LA + 8192 + (wm + 64 + i * 16 + fr) * 32 + cA);
    if (!lastit) { STG32(LB, gB, 1, 0, t + 3); }
    BAR(); MFQ32(4, 0, b0); BAR();

    // phase 8: stage B(t+3) h1 | vmcnt guard for next buf0 | MFMA q(4,2)
    if (!lastit) { STG32(LB, gB, 1, 1, t + 3); VMCNT(2); }
    BAR(); MFQ32(4, 2, b1); BAR();
  }

  // epilogue: C/D layout col=lane&15, row=(lane>>4)*4+reg (R12-proven form)
#pragma unroll
  for (int i = 0; i < 8; i++) {
    const int row = m0 + wm + i * 16 + fq * 4;
#pragma unroll
    for (int j = 0; j < 4; j++) {
      const int col = n0 + wn + j * 16 + fr;
      const float bv = bias[col];
#pragma unroll
      for (int q = 0; q < 4; q++)
        C[(size_t)(row + q) * NQ + col] = (f16)(acc[i][j][q] + bv);
    }
  }
}

// ---------------- 128^2 GEMM, BK=64, two stride-32 sub-buffers (proj) ----------
// + bijective XCD swizzle: 320 blocks = 8 XCD x 40; each XCD keeps wproj's
// 3.3 MB B-panel L2-resident across its 40 blocks.
template<int OUT_F32>
__global__ __launch_bounds__(256) void gemm_bt64(const f16* __restrict__ A,
                                                 const f16* __restrict__ B,
                                                 const float* __restrict__ bias,
                                                 void* __restrict__ C,
                                                 int M, int N, int K,
                                                 int nbx, int cpx) {
  __shared__ __align__(16) f16 AsF[8192];   // [2 sub][128][32]
  __shared__ __align__(16) f16 BsF[8192];
  const int tid = threadIdx.x;
  const int w = tid >> 6, l = tid & 63;
  const int bid = (blockIdx.x & 7) * cpx + (blockIdx.x >> 3);
  const int m0 = (bid / nbx) * 128, n0 = (bid % nbx) * 128;
  const int wm = (w >> 1) * 64, wn = (w & 1) * 64;
  const int fr = l & 15, fg = (l >> 4) * 8;

  size_t aoff[4], boff[4];
#pragma unroll
  for (int i = 0; i < 4; i++) {
    const int d = i * 256 + tid;
    const int sub = d >> 9, dd = d & 511;
    const int r = dd >> 2, c = (dd & 3) + sub * 4;
    aoff[i] = (size_t)(m0 + r) * K + c * 8;
    boff[i] = (size_t)(n0 + r) * K + c * 8;
  }

  f32x4 acc[4][4] = {};

  for (int k0 = 0; k0 < K; k0 += 64) {
    if (k0) __syncthreads();
#pragma unroll
    for (int i = 0; i < 4; i++) gload16(A + aoff[i] + k0, AsF + (i * 256 + tid) * 8);
#pragma unroll
    for (int i = 0; i < 4; i++) gload16(B + boff[i] + k0, BsF + (i * 256 + tid) * 8);
    __syncthreads();
    f16x8 af[4][2], bf[4][2];
#pragma unroll
    for (int i = 0; i < 4; i++)
#pragma unroll
      for (int s = 0; s < 2; s++) {
        af[i][s] = *(const f16x8*)(AsF + s * 4096 + (wm + i * 16 + fr) * 32 + fg);
        bf[i][s] = *(const f16x8*)(BsF + s * 4096 + (wn + i * 16 + fr) * 32 + fg);
      }
#pragma unroll
    for (int i = 0; i < 4; i++)
#pragma unroll
      for (int j = 0; j < 4; j++)
#pragma unroll
        for (int s = 0; s < 2; s++)
          acc[i][j] = __builtin_amdgcn_mfma_f32_16x16x32_f16(af[i][s], bf[j][s], acc[i][j], 0, 0, 0);
  }

  const int q4 = (l >> 4) * 4;
#pragma unroll
  for (int i = 0; i < 4; i++) {
    const int row = m0 + wm + i * 16 + q4;
#pragma unroll
    for (int j = 0; j < 4; j++) {
      const int col = n0 + wn + j * 16 + fr;
      const float bv = bias[col];
#pragma unroll
      for (int q = 0; q < 4; q++) {
        float v = acc[i][j][q] + bv;
        if (OUT_F32) ((float*)C)[(size_t)(row + q) * N + col] = v;
        else         ((f16*)C)[(size_t)(row + q) * N + col] = (f16)v;
      }
    }
  }
}

// ---------------- prep: fused vectorized RoPE + V transpose --------------------
#define RPB 1280
__global__ __launch_bounds__(256) void prep_kernel(const f16* __restrict__ qkvb,
                                                   const float* __restrict__ rpe,
                                                   f16* __restrict__ qh,
                                                   f16* __restrict__ kh,
                                                   f16* __restrict__ vt) {
  __shared__ f16 tile[HD][65];
  const int b = blockIdx.x;
  if (b < RPB) {
    const float SCLT = 0.1118033988749895f * 1.4426950408889634f;  // 1/sqrt(80)*log2e
    const int t = b * 256 + threadIdx.x;          // < SEQ*NH*5
    const int d8 = (t % 5) * 8;
    const int h = (t / 5) % NH;
    const int s = t / (5 * NH);
    const f32x4 f0 = *(const f32x4*)(rpe + s * 40 + d8);
    const f32x4 f1 = *(const f32x4*)(rpe + s * 40 + d8 + 4);
    const f16* base = qkvb + (size_t)s * (3 * HIDN) + h * HD;
    const f16x8 q0 = *(const f16x8*)(base + d8);
    const f16x8 q1 = *(const f16x8*)(base + 40 + d8);
    const f16x8 k0 = *(const f16x8*)(base + HIDN + d8);
    const f16x8 k1 = *(const f16x8*)(base + HIDN + 40 + d8);
    f16x8 oq0, oq1, ok0, ok1;
#pragma unroll
    for (int j = 0; j < 8; j++) {
      const float fv = (j < 4) ? f0[j] : f1[j - 4];
      float sn, cs;
      __sincosf(fv, &sn, &cs);
      const float a = (float)q0[j], bq = (float)q1[j];
      oq0[j] = (f16)((a * cs - bq * sn) * SCLT);
      oq1[j] = (f16)((bq * cs + a * sn) * SCLT);
      const float ka = (float)k0[j], kb = (float)k1[j];
      ok0[j] = (f16)(ka * cs - kb * sn);
      ok1[j] = (f16)(kb * cs + ka * sn);
    }
    const size_t ob = ((size_t)h * SEQ + s) * DP;
    *(f16x8*)(qh + ob + d8)      = oq0;
    *(f16x8*)(qh + ob + 40 + d8) = oq1;
    *(f16x8*)(kh + ob + d8)      = ok0;
    *(f16x8*)(kh + ob + 40 + d8) = ok1;
    if (d8 == 32) {      // zero the [80,96) pad
      const f16x8 z = {};
      *(f16x8*)(qh + ob + 80) = z; *(f16x8*)(qh + ob + 88) = z;
      *(f16x8*)(kh + ob + 80) = z; *(f16x8*)(kh + ob + 88) = z;
    }
  } else {
    const int bb = b - RPB;
    const int h = bb >> 6;
    const int s0 = (bb & 63) * 64;
    for (int idx = threadIdx.x; idx < 64 * HD; idx += 256) {
      const int sr = idx / HD, d = idx % HD;
      tile[d][sr] = qkvb[(size_t)(s0 + sr) * (3 * HIDN) + 2 * HIDN + h * HD + d];
    }
    __syncthreads();
    // kv-permuted within 32-blocks: slot s -> actual kv matches MFMA k-slot order
    for (int idx = threadIdx.x; idx < HD * 64; idx += 256) {
      const int d = idx >> 6, sc = idx & 63;
      const int blk = sc >> 5, s = sc & 31, g = s >> 3, j = s & 7;
      const int act = blk * 32 + ((j < 4) ? (4 * g + j) : (16 + 4 * g + (j - 4)));
      vt[((size_t)h * HD + d) * SEQ + s0 + sc] = tile[d][act];
    }
  }
}

// ---------------- Flash attention: QBLK=256, 64 q-rows/wave (R12-proven) -------
__global__ __launch_bounds__(512, 2) void attn_kernel(const f16* __restrict__ qh,
                                                      const f16* __restrict__ kh,
                                                      const f16* __restrict__ vt,
                                                      const int* __restrict__ cu,
                                                      f16* __restrict__ ao) {
  __shared__ __align__(16) f16 smem[2 * HSZ];        // 62,464 B
  const int tid = threadIdx.x, w = tid >> 6, l = tid & 63;
  const int grp = w >> 2, wq = w & 3;
  const int bid = blockIdx.x;
  const int g = bid & 63, ib = bid >> 6;             // ib in 0..3
  const int h = g >> 2;
  const int qblk = ((g & 3) * 4 + ib) * 256;
  int seg = 0;
  while (cu[seg + 1] <= qblk) seg++;
  const int kvb = cu[seg], kve = cu[seg + 1];
  const int nt = (kve - kvb + 63) >> 6;
  const int fr = l & 15, fg = (l >> 4) * 8;
  const int row0 = qblk + wq * 64;

  // Q fragments for 4 subtiles (B-operand of swapped QK^T; q pre-scaled)
  const f16* qb = qh + ((size_t)h * SEQ + row0 + fr) * DP + fg;
  f16x8 aq[4][3];
#pragma unroll
  for (int u = 0; u < 4; u++)
#pragma unroll
    for (int kk = 0; kk < 3; kk++)
      aq[u][kk] = *(const f16x8*)(qb + u * 16 * DP + kk * 32);

  // staging decode: K = 768 chunks (2 grp x 32 r x 12 c), V = 640 (2 x 80 x 4)
  const int k0g = tid / 384, k0r = (tid % 384) / 12, k0c = tid % 12;
  const int k1r = (128 + tid) / 12, k1c = (128 + tid) % 12;       // chunk 512+tid, grp1
  const int v0g = tid / 320, v0r = (tid % 320) / 4, v0c = tid & 3;
  const int v1r = (192 + tid) >> 2, v1c = (192 + tid) & 3;        // chunk 512+tid, grp1
  const f16* kp0 = kh + ((size_t)h * SEQ + kvb + k0g * 32 + k0r) * DP + k0c * 8;
  const f16* kp1 = kh + ((size_t)h * SEQ + kvb + 32 + k1r) * DP + k1c * 8;
  const f16* vp0 = vt + ((size_t)h * HD + v0r) * SEQ + kvb + v0g * 32 + v0c * 8;
  const f16* vp1 = vt + ((size_t)h * HD + v1r) * SEQ + kvb + 32 + v1c * 8;
  const int dK0 = k0g * KSZ + k0r * 104 + k0c * 8;
  const int dK1 = KSZ + k1r * 104 + k1c * 8;
  const int dV0 = 2 * KSZ + v0g * VSZ + v0r * 56 + v0c * 8;
  const int dV1 = 2 * KSZ + VSZ + v1r * 56 + v1c * 8;

  float m = -1e30f;
  float ls[4] = {0.f, 0.f, 0.f, 0.f};
  f32x4 o[4][5] = {};

  // prologue: load tile 0 -> regs -> buf 0
  uint4 rk0, rk1, rv0, rv1;
  rk0 = *(const uint4*)kp0;
  if (tid < 256) rk1 = *(const uint4*)kp1;
  rv0 = *(const uint4*)vp0;
  if (tid < 128) rv1 = *(const uint4*)vp1;
  *(uint4*)(smem + dK0) = rk0;
  if (tid < 256) *(uint4*)(smem + dK1) = rk1;
  *(uint4*)(smem + dV0) = rv0;
  if (tid < 128) *(uint4*)(smem + dV1) = rv1;
  __syncthreads();

  for (int t = 0; t < nt; t++) {
    const int p = t & 1;
    const int off = (t + 1) * 64;            // next-tile offset
    const bool more = (t + 1 < nt);

    if (more) {                              // issue next-tile loads (T14: early)
      rk0 = *(const uint4*)(kp0 + (size_t)off * DP);
      if (tid < 256) rk1 = *(const uint4*)(kp1 + (size_t)off * DP);
      rv0 = *(const uint4*)(vp0 + off);
      if (tid < 128) rv1 = *(const uint4*)(vp1 + off);
    }

    // compute from buf p (my grp's tiles)
    const f16* myK = smem + p * HSZ + grp * KSZ;
    const f16* myV = smem + p * HSZ + 2 * KSZ + grp * VSZ;

    f32x4 s[4][2] = {};
    __builtin_amdgcn_s_setprio(1);
#pragma unroll
    for (int kk = 0; kk < 3; kk++) {
      const f16x8 k0 = *(const f16x8*)(myK + fr * 104 + kk * 32 + fg);
      const f16x8 k1 = *(const f16x8*)(myK + (16 + fr) * 104 + kk * 32 + fg);
#pragma unroll
      for (int u = 0; u < 4; u++) {
        s[u][0] = __builtin_amdgcn_mfma_f32_16x16x32_f16(k0, aq[u][kk], s[u][0], 0, 0, 0);
        s[u][1] = __builtin_amdgcn_mfma_f32_16x16x32_f16(k1, aq[u][kk], s[u][1], 0, 0, 0);
      }
    }
    __builtin_amdgcn_s_setprio(0);

    // per-lane max + wave vote; full reduce + rescale only when needed (rare)
    float pmax = s[0][0][0];
#pragma unroll
    for (int u = 0; u < 4; u++)
#pragma unroll
      for (int j = 0; j < 4; j++)
        pmax = fmaxf(pmax, fmaxf(s[u][0][j], s[u][1][j]));
    if (__any(pmax > m + 8.f)) {
      float tmax = pmax;
      tmax = fmaxf(tmax, __shfl_xor(tmax, 1));
      tmax = fmaxf(tmax, __shfl_xor(tmax, 2));
      tmax = fmaxf(tmax, __shfl_xor(tmax, 4));
      tmax = fmaxf(tmax, __shfl_xor(tmax, 8));
      tmax = fmaxf(tmax, __shfl_xor(tmax, 16));
      tmax = fmaxf(tmax, __shfl_xor(tmax, 32));
      const float aa = __builtin_amdgcn_exp2f(m - tmax);
      m = tmax;
#pragma unroll
      for (int u = 0; u < 4; u++) {
        ls[u] *= aa;
#pragma unroll
        for (int dt = 0; dt < 5; dt++)
#pragma unroll
          for (int j = 0; j < 4; j++) o[u][dt][j] *= aa;
      }
    }

    // P = exp2(S - m) in-place, accumulate row sums, pack to PV A-fragments
    f16x8 pa[4];
#pragma unroll
    for (int u = 0; u < 4; u++) {
#pragma unroll
      for (int r = 0; r < 4; r++) {
        s[u][0][r] = __builtin_amdgcn_exp2f(s[u][0][r] - m);
        s[u][1][r] = __builtin_amdgcn_exp2f(s[u][1][r] - m);
        ls[u] += s[u][0][r] + s[u][1][r];
      }
      uint4 ua;
      ua.x = pk2(s[u][0][0], s[u][0][1]); ua.y = pk2(s[u][0][2], s[u][0][3]);
      ua.z = pk2(s[u][1][0], s[u][1][1]); ua.w = pk2(s[u][1][2], s[u][1][3]);
      pa[u] = bc16(ua);
    }

    __builtin_amdgcn_s_setprio(1);
#pragma unroll
    for (int dt = 0; dt < 5; dt++) {
      const f16x8 bv = *(const f16x8*)(myV + (dt * 16 + fr) * 56 + fg);
#pragma unroll
      for (int u = 0; u < 4; u++)
        o[u][dt] = __builtin_amdgcn_mfma_f32_16x16x32_f16(pa[u], bv, o[u][dt], 0, 0, 0);
    }
    __builtin_amdgcn_s_setprio(0);

    if (more) {                              // write next tile (T14: late)
      f16* dst = smem + (1 - p) * HSZ;
      *(uint4*)(dst + dK0) = rk0;
      if (tid < 256) *(uint4*)(dst + dK1) = rk1;
      *(uint4*)(dst + dV0) = rv0;
      if (tid < 128) *(uint4*)(dst + dV1) = rv1;
    }
    __syncthreads();                         // single barrier per iteration
  }

  // finish per-subtile row sums (partials spread across g = l>>4)
#pragma unroll
  for (int u = 0; u < 4; u++) {
    ls[u] += __shfl_xor(ls[u], 16);
    ls[u] += __shfl_xor(ls[u], 32);
  }

  // merge kv-halves in 2 phases (subtiles 0,1 then 2,3); 44 KB merge buf
  float* mb = (float*)smem;
  float aA = 1.f, aB = 0.f;
  if (grp == 1) {
    float* dst = mb + (wq * 64 + l) * 43;
    dst[0] = m; dst[1] = ls[0]; dst[2] = ls[1];
#pragma unroll
    for (int u = 0; u < 2; u++)
#pragma unroll
      for (int dt = 0; dt < 5; dt++)
#pragma unroll
        for (int j = 0; j < 4; j++)
          dst[3 + u * 20 + dt * 4 + j] = o[u][dt][j];
  }
  __syncthreads();
  if (grp == 0) {
    const float* src = mb + (wq * 64 + l) * 43;
    const float mB = src[0];
    const float M = fmaxf(m, mB);
    aA = __builtin_amdgcn_exp2f(m - M);
    aB = __builtin_amdgcn_exp2f(mB - M);
    ls[0] = ls[0] * aA + src[1] * aB;
    ls[1] = ls[1] * aA + src[2] * aB;
#pragma unroll
    for (int u = 0; u < 2; u++)
#pragma unroll
      for (int dt = 0; dt < 5; dt++)
#pragma unroll
        for (int j = 0; j < 4; j++)
          o[u][dt][j] = o[u][dt][j] * aA + src[3 + u * 20 + dt * 4 + j] * aB;
  }
  __syncthreads();
  if (grp == 1) {
    float* dst = mb + (wq * 64 + l) * 42;
    dst[0] = ls[2]; dst[1] = ls[3];
#pragma unroll
    for (int u = 2; u < 4; u++)
#pragma unroll
      for (int dt = 0; dt < 5; dt++)
#pragma unroll
        for (int j = 0; j < 4; j++)
          dst[2 + (u - 2) * 20 + dt * 4 + j] = o[u][dt][j];
  }
  __syncthreads();
  if (grp == 0) {
    const float* src = mb + (wq * 64 + l) * 42;
    ls[2] = ls[2] * aA + src[0] * aB;
    ls[3] = ls[3] * aA + src[1] * aB;
#pragma unroll
    for (int u = 2; u < 4; u++)
#pragma unroll
      for (int dt = 0; dt < 5; dt++)
#pragma unroll
        for (int j = 0; j < 4; j++)
          o[u][dt][j] = o[u][dt][j] * aA + src[2 + (u - 2) * 20 + dt * 4 + j] * aB;

    // redistribute 1/rowsum (indexed by q=l&15) to o-rows (q'=4*(l>>4)+j)
#pragma unroll
    for (int u = 0; u < 4; u++) {
      const float inv = 1.0f / ls[u];
      float iv[4];
#pragma unroll
      for (int j = 0; j < 4; j++) {
        const int srcl = (l & 48) | ((l >> 4) * 4 + j);
        iv[j] = __shfl(inv, srcl);
      }
      const int orow = row0 + u * 16 + (l >> 4) * 4;
#pragma unroll
      for (int dt = 0; dt < 5; dt++)
#pragma unroll
        for (int j = 0; j < 4; j++)
          ao[(size_t)(orow + j) * HIDN + h * HD + dt * 16 + fr] = (f16)(o[u][dt][j] * iv[j]);
    }
  }
}

extern "C" void kernel_launch(void* const* d_in, const int* in_sizes, int n_in,
                              void* d_out, int out_size, void* d_ws, size_t ws_size,
                              hipStream_t stream) {
  const float* x      = (const float*)d_in[0];
  const int*   cu     = (const int*)d_in[1];
  const float* rpe    = (const float*)d_in[2];
  const float* qkv_w  = (const float*)d_in[3];
  const float* qkv_b  = (const float*)d_in[4];
  const float* proj_w = (const float*)d_in[5];
  const float* proj_b = (const float*)d_in[6];

  char* ws = (char*)d_ws;
  f16* xb    = (f16*)(ws);              // [4096][1280]
  f16* wqkv  = (f16*)(ws + 10485760);   // [3840][1280]
  f16* wproj = (f16*)(ws + 20316160);   // [1280][1280]
  f16* qkvb  = (f16*)(ws + 23592960);   // [4096][3840]
  f16* qh    = (f16*)(ws + 55050240);   // [16][4096][96]
  f16* kh    = (f16*)(ws + 67633152);   // [16][4096][96]
  f16* vt    = (f16*)(ws + 80216064);   // [16][80][4096] (kv-permuted)
  f16* ao    = xb;

  const int n0 = SEQ * HIDN, n1 = 3 * HIDN * HIDN, n2 = HIDN * HIDN;
  cvt3_kernel<<<(n0 + n1 + n2) / (256 * 8), 256, 0, stream>>>(
      x, qkv_w, proj_w, xb, wqkv, wproj, n0, n1, n2);

  qkv_gemm8<<<240, 512, 0, stream>>>(xb, wqkv, qkv_b, qkvb);

  prep_kernel<<<RPB + 1024, 256, 0, stream>>>(qkvb, rpe, qh, kh, vt);

  attn_kernel<<<256, 512, 0, stream>>>(qh, kh, vt, cu, ao);

  // proj: 320 blocks = 8 XCD x 40, nbx = 1280/128 = 10
  gemm_bt64<1><<<320, 256, 0, stream>>>(
      ao, wproj, proj_b, d_out, SEQ, HIDN, HIDN, 10, 40);
}

// Round 14
// 132.383 us; speedup vs baseline: 3.6228x; 3.6228x over previous
//
#include <hip/hip_runtime.h>

typedef _Float16 f16;
typedef __attribute__((ext_vector_type(8))) _Float16 f16x8;
typedef __attribute__((ext_vector_type(4))) float f32x4;

#define SEQ   4096
#define NH    16
#define HD    80
#define HIDN  1280
#define DP    96

// attn LDS geometry (R8-proven)
#define KSZ   3328          // 32 rows x 104 (padded) f16
#define VSZ   4480          // 80 rows x 56 (padded) f16
#define HSZ   (2*KSZ + 2*VSZ)   // one double-buffer half: 15616 f16 = 31,232 B

// 8-phase GEMM constants (QKV: M=4096, N=3840, K=1280)
#define KQ   1280
#define NQ   3840
#define NIT  10      // K / 128

__device__ __forceinline__ void gload16(const void* g, void* l) {
  __builtin_amdgcn_global_load_lds(
      (const __attribute__((address_space(1))) unsigned int*)g,
      (__attribute__((address_space(3))) unsigned int*)l, 16, 0, 0);
}

__device__ __forceinline__ unsigned pk2(float a, float b) {
  return __builtin_bit_cast(unsigned, __builtin_amdgcn_cvt_pkrtz(a, b));
}
__device__ __forceinline__ f16x8 bc16(uint4 u) { return __builtin_bit_cast(f16x8, u); }

#define BAR() __builtin_amdgcn_s_barrier()
#define VMCNT(n) do { asm volatile("s_waitcnt vmcnt(" #n ")" ::: "memory"); \
                      __builtin_amdgcn_sched_barrier(0); } while (0)
#define STG(Lb, g, buf, h, kt)                                                  \
  do {                                                                          \
    gload16((g) + (size_t)((h) * 128) * KQ + (kt) * 64,                         \
            (Lb) + (buf) * 16384 + ((h) * 128) * 64 + w * 512);                 \
    gload16((g) + (size_t)((h) * 128 + 64) * KQ + (kt) * 64,                    \
            (Lb) + (buf) * 16384 + ((h) * 128 + 64) * 64 + w * 512);            \
  } while (0)
#define MFQ(IOFF, JOFF, BB)                                                     \
  do {                                                                          \
    __builtin_amdgcn_s_setprio(1);                                              \
    _Pragma("unroll")                                                           \
    for (int i_ = 0; i_ < 4; i_++)                                              \
      _Pragma("unroll")                                                         \
      for (int j_ = 0; j_ < 2; j_++)                                            \
        _Pragma("unroll")                                                       \
        for (int s_ = 0; s_ < 2; s_++)                                          \
          acc[i_ + IOFF][j_ + JOFF] = __builtin_amdgcn_mfma_f32_16x16x32_f16(   \
              a[i_][s_], BB[j_][s_], acc[i_ + IOFF][j_ + JOFF], 0, 0, 0);       \
    __builtin_amdgcn_s_setprio(0);                                              \
  } while (0)

// ---------------- fused f32 -> f16 convert for x, qkv_w, proj_w ----------------
__global__ __launch_bounds__(256) void cvt3_kernel(const float* __restrict__ s0,
                                                   const float* __restrict__ s1,
                                                   const float* __restrict__ s2,
                                                   f16* __restrict__ d0,
                                                   f16* __restrict__ d1,
                                                   f16* __restrict__ d2,
                                                   int n0, int n1, int n2) {
  long i = (long)(blockIdx.x * 256 + threadIdx.x) * 8;
  const float* s; f16* d;
  if (i < n0)                { s = s0 + i;            d = d0 + i; }
  else if (i < n0 + n1)      { s = s1 + (i - n0);     d = d1 + (i - n0); }
  else if (i < n0 + n1 + n2) { s = s2 + (i - n0 - n1); d = d2 + (i - n0 - n1); }
  else return;
  f32x4 v0 = *(const f32x4*)(s);
  f32x4 v1 = *(const f32x4*)(s + 4);
  f16x8 o;
#pragma unroll
  for (int j = 0; j < 4; j++) { o[j] = (f16)v0[j]; o[4 + j] = (f16)v1[j]; }
  *(f16x8*)(d) = o;
}

// ---------------- 8-phase 256^2 GEMM: C[4096][3840] = A * B^T + bias (f16 out) ----
// R12-proven: BK=64, 128 KB LDS, counted vmcnt(4), T2 chunk swizzle, 48.6 us.
__global__ __launch_bounds__(512, 2) void qkv_gemm8(const f16* __restrict__ A,
                                                    const f16* __restrict__ B,
                                                    const float* __restrict__ bias,
                                                    f16* __restrict__ C) {
  __shared__ __align__(16) f16 LA[2 * 16384];
  __shared__ __align__(16) f16 LB[2 * 16384];
  const int tid = threadIdx.x, w = tid >> 6, l = tid & 63;
  const int bid = (blockIdx.x & 7) * 30 + (blockIdx.x >> 3);
  const int bx = bid % 15, by = bid / 15;
  const int m0 = by * 256, n0 = bx * 256;
  const int wm = (w >> 2) * 128, wn = (w & 3) * 64;
  const int fr = l & 15, fq = l >> 4;
  const int rx = fr & 7;
  const int cA0 = (fq ^ rx) * 8;
  const int cA1 = ((4 + fq) ^ rx) * 8;

  const int srow = w * 8 + (l >> 3);
  const int scol = ((l & 7) ^ (l >> 3)) * 8;
  const f16* gA = A + (size_t)(m0 + srow) * KQ + scol;
  const f16* gB = B + (size_t)(n0 + srow) * KQ + scol;

  f32x4 acc[8][4] = {};
  f16x8 a[4][2], b0[2][2], b1[2][2];

  STG(LA, gA, 0, 0, 0); STG(LA, gA, 0, 1, 0);
  STG(LB, gB, 0, 0, 0); STG(LB, gB, 0, 1, 0);
  STG(LB, gB, 1, 0, 1); STG(LB, gB, 1, 1, 1);
  VMCNT(4);
  BAR();

  for (int it = 0; it < NIT; ++it) {
    const int t = 2 * it;
    const bool lastit = (it == NIT - 1);

#pragma unroll
    for (int i = 0; i < 4; i++) {
      a[i][0] = *(const f16x8*)(LA + (wm + i * 16 + fr) * 64 + cA0);
      a[i][1] = *(const f16x8*)(LA + (wm + i * 16 + fr) * 64 + cA1);
    }
#pragma unroll
    for (int j = 0; j < 2; j++) {
      b0[j][0] = *(const f16x8*)(LB + (wn + j * 16 + fr) * 64 + cA0);
      b0[j][1] = *(const f16x8*)(LB + (wn + j * 16 + fr) * 64 + cA1);
    }
    STG(LA, gA, 1, 0, t + 1);
    BAR(); MFQ(0, 0, b0); BAR();

#pragma unroll
    for (int j = 0; j < 2; j++) {
      b1[j][0] = *(const f16x8*)(LB + (wn + 32 + j * 16 + fr) * 64 + cA0);
      b1[j][1] = *(const f16x8*)(LB + (wn + 32 + j * 16 + fr) * 64 + cA1);
    }
    STG(LA, gA, 1, 1, t + 1);
    BAR(); MFQ(0, 2, b1); BAR();

#pragma unroll
    for (int i = 0; i < 4; i++) {
      a[i][0] = *(const f16x8*)(LA + (wm + 64 + i * 16 + fr) * 64 + cA0);
      a[i][1] = *(const f16x8*)(LA + (wm + 64 + i * 16 + fr) * 64 + cA1);
    }
    if (!lastit) { STG(LB, gB, 0, 0, t + 2); }
    BAR(); MFQ(4, 0, b0); BAR();

    if (!lastit) { STG(LB, gB, 0, 1, t + 2); VMCNT(4); }
    else         { VMCNT(0); }
    BAR(); MFQ(4, 2, b1); BAR();

#pragma unroll
    for (int i = 0; i < 4; i++) {
      a[i][0] = *(const f16x8*)(LA + 16384 + (wm + i * 16 + fr) * 64 + cA0);
      a[i][1] = *(const f16x8*)(LA + 16384 + (wm + i * 16 + fr) * 64 + cA1);
    }
#pragma unroll
    for (int j = 0; j < 2; j++) {
      b0[j][0] = *(const f16x8*)(LB + 16384 + (wn + j * 16 + fr) * 64 + cA0);
      b0[j][1] = *(const f16x8*)(LB + 16384 + (wn + j * 16 + fr) * 64 + cA1);
    }
    if (!lastit) { STG(LA, gA, 0, 0, t + 2); }
    BAR(); MFQ(0, 0, b0); BAR();

#pragma unroll
    for (int j = 0; j < 2; j++) {
      b1[j][0] = *(const f16x8*)(LB + 16384 + (wn + 32 + j * 16 + fr) * 64 + cA0);
      b1[j][1] = *(const f16x8*)(LB + 16384 + (wn + 32 + j * 16 + fr) * 64 + cA1);
    }
    if (!lastit) { STG(LA, gA, 0, 1, t + 2); }
    BAR(); MFQ(0, 2, b1); BAR();

#pragma unroll
    for (int i = 0; i < 4; i++) {
      a[i][0] = *(const f16x8*)(LA + 16384 + (wm + 64 + i * 16 + fr) * 64 + cA0);
      a[i][1] = *(const f16x8*)(LA + 16384 + (wm + 64 + i * 16 + fr) * 64 + cA1);
    }
    if (!lastit) { STG(LB, gB, 1, 0, t + 3); }
    BAR(); MFQ(4, 0, b0); BAR();

    if (!lastit) { STG(LB, gB, 1, 1, t + 3); VMCNT(4); }
    BAR(); MFQ(4, 2, b1); BAR();
  }

#pragma unroll
  for (int i = 0; i < 8; i++) {
    const int row = m0 + wm + i * 16 + fq * 4;
#pragma unroll
    for (int j = 0; j < 4; j++) {
      const int col = n0 + wn + j * 16 + fr;
      const float bv = bias[col];
#pragma unroll
      for (int q = 0; q < 4; q++)
        C[(size_t)(row + q) * NQ + col] = (f16)(acc[i][j][q] + bv);
    }
  }
}

// ---------------- 128^2 GEMM, BK=64, two stride-32 sub-buffers (proj) ----------
// + bijective XCD swizzle: 320 blocks = 8 XCD x 40; wproj's 3.3 MB B-panel
// stays L2-resident per XCD.
template<int OUT_F32>
__global__ __launch_bounds__(256) void gemm_bt64(const f16* __restrict__ A,
                                                 const f16* __restrict__ B,
                                                 const float* __restrict__ bias,
                                                 void* __restrict__ C,
                                                 int M, int N, int K,
                                                 int nbx, int cpx) {
  __shared__ __align__(16) f16 AsF[8192];   // [2 sub][128][32]
  __shared__ __align__(16) f16 BsF[8192];
  const int tid = threadIdx.x;
  const int w = tid >> 6, l = tid & 63;
  const int bid = (blockIdx.x & 7) * cpx + (blockIdx.x >> 3);
  const int m0 = (bid / nbx) * 128, n0 = (bid % nbx) * 128;
  const int wm = (w >> 1) * 64, wn = (w & 1) * 64;
  const int fr = l & 15, fg = (l >> 4) * 8;

  size_t aoff[4], boff[4];
#pragma unroll
  for (int i = 0; i < 4; i++) {
    const int d = i * 256 + tid;
    const int sub = d >> 9, dd = d & 511;
    const int r = dd >> 2, c = (dd & 3) + sub * 4;
    aoff[i] = (size_t)(m0 + r) * K + c * 8;
    boff[i] = (size_t)(n0 + r) * K + c * 8;
  }

  f32x4 acc[4][4] = {};

  for (int k0 = 0; k0 < K; k0 += 64) {
    if (k0) __syncthreads();
#pragma unroll
    for (int i = 0; i < 4; i++) gload16(A + aoff[i] + k0, AsF + (i * 256 + tid) * 8);
#pragma unroll
    for (int i = 0; i < 4; i++) gload16(B + boff[i] + k0, BsF + (i * 256 + tid) * 8);
    __syncthreads();
    f16x8 af[4][2], bf[4][2];
#pragma unroll
    for (int i = 0; i < 4; i++)
#pragma unroll
      for (int s = 0; s < 2; s++) {
        af[i][s] = *(const f16x8*)(AsF + s * 4096 + (wm + i * 16 + fr) * 32 + fg);
        bf[i][s] = *(const f16x8*)(BsF + s * 4096 + (wn + i * 16 + fr) * 32 + fg);
      }
#pragma unroll
    for (int i = 0; i < 4; i++)
#pragma unroll
      for (int j = 0; j < 4; j++)
#pragma unroll
        for (int s = 0; s < 2; s++)
          acc[i][j] = __builtin_amdgcn_mfma_f32_16x16x32_f16(af[i][s], bf[j][s], acc[i][j], 0, 0, 0);
  }

  const int q4 = (l >> 4) * 4;
#pragma unroll
  for (int i = 0; i < 4; i++) {
    const int row = m0 + wm + i * 16 + q4;
#pragma unroll
    for (int j = 0; j < 4; j++) {
      const int col = n0 + wn + j * 16 + fr;
      const float bv = bias[col];
#pragma unroll
      for (int q = 0; q < 4; q++) {
        float v = acc[i][j][q] + bv;
        if (OUT_F32) ((float*)C)[(size_t)(row + q) * N + col] = v;
        else         ((f16*)C)[(size_t)(row + q) * N + col] = (f16)v;
      }
    }
  }
}

// ---------------- prep: fused vectorized RoPE + V transpose --------------------
#define RPB 1280
__global__ __launch_bounds__(256) void prep_kernel(const f16* __restrict__ qkvb,
                                                   const float* __restrict__ rpe,
                                                   f16* __restrict__ qh,
                                                   f16* __restrict__ kh,
                                                   f16* __restrict__ vt) {
  __shared__ f16 tile[HD][65];
  const int b = blockIdx.x;
  if (b < RPB) {
    const float SCLT = 0.1118033988749895f * 1.4426950408889634f;  // 1/sqrt(80)*log2e
    const int t = b * 256 + threadIdx.x;          // < SEQ*NH*5
    const int d8 = (t % 5) * 8;
    const int h = (t / 5) % NH;
    const int s = t / (5 * NH);
    const f32x4 f0 = *(const f32x4*)(rpe + s * 40 + d8);
    const f32x4 f1 = *(const f32x4*)(rpe + s * 40 + d8 + 4);
    const f16* base = qkvb + (size_t)s * (3 * HIDN) + h * HD;
    const f16x8 q0 = *(const f16x8*)(base + d8);
    const f16x8 q1 = *(const f16x8*)(base + 40 + d8);
    const f16x8 k0 = *(const f16x8*)(base + HIDN + d8);
    const f16x8 k1 = *(const f16x8*)(base + HIDN + 40 + d8);
    f16x8 oq0, oq1, ok0, ok1;
#pragma unroll
    for (int j = 0; j < 8; j++) {
      const float fv = (j < 4) ? f0[j] : f1[j - 4];
      float sn, cs;
      __sincosf(fv, &sn, &cs);
      const float a = (float)q0[j], bq = (float)q1[j];
      oq0[j] = (f16)((a * cs - bq * sn) * SCLT);
      oq1[j] = (f16)((bq * cs + a * sn) * SCLT);
      const float ka = (float)k0[j], kb = (float)k1[j];
      ok0[j] = (f16)(ka * cs - kb * sn);
      ok1[j] = (f16)(kb * cs + ka * sn);
    }
    const size_t ob = ((size_t)h * SEQ + s) * DP;
    *(f16x8*)(qh + ob + d8)      = oq0;
    *(f16x8*)(qh + ob + 40 + d8) = oq1;
    *(f16x8*)(kh + ob + d8)      = ok0;
    *(f16x8*)(kh + ob + 40 + d8) = ok1;
    if (d8 == 32) {      // zero the [80,96) pad
      const f16x8 z = {};
      *(f16x8*)(qh + ob + 80) = z; *(f16x8*)(qh + ob + 88) = z;
      *(f16x8*)(kh + ob + 80) = z; *(f16x8*)(kh + ob + 88) = z;
    }
  } else {
    const int bb = b - RPB;
    const int h = bb >> 6;
    const int s0 = (bb & 63) * 64;
    for (int idx = threadIdx.x; idx < 64 * HD; idx += 256) {
      const int sr = idx / HD, d = idx % HD;
      tile[d][sr] = qkvb[(size_t)(s0 + sr) * (3 * HIDN) + 2 * HIDN + h * HD + d];
    }
    __syncthreads();
    // kv-permuted within 32-blocks: slot s -> actual kv matches MFMA k-slot order
    for (int idx = threadIdx.x; idx < HD * 64; idx += 256) {
      const int d = idx >> 6, sc = idx & 63;
      const int blk = sc >> 5, s = sc & 31, g = s >> 3, j = s & 7;
      const int act = blk * 32 + ((j < 4) ? (4 * g + j) : (16 + 4 * g + (j - 4)));
      vt[((size_t)h * HD + d) * SEQ + s0 + sc] = tile[d][act];
    }
  }
}

// ---------------- Flash attention: QBLK=256, 64 q-rows/wave (R12-proven) -------
__global__ __launch_bounds__(512, 2) void attn_kernel(const f16* __restrict__ qh,
                                                      const f16* __restrict__ kh,
                                                      const f16* __restrict__ vt,
                                                      const int* __restrict__ cu,
                                                      f16* __restrict__ ao) {
  __shared__ __align__(16) f16 smem[2 * HSZ];        // 62,464 B
  const int tid = threadIdx.x, w = tid >> 6, l = tid & 63;
  const int grp = w >> 2, wq = w & 3;
  const int bid = blockIdx.x;
  const int g = bid & 63, ib = bid >> 6;             // ib in 0..3
  const int h = g >> 2;
  const int qblk = ((g & 3) * 4 + ib) * 256;
  int seg = 0;
  while (cu[seg + 1] <= qblk) seg++;
  const int kvb = cu[seg], kve = cu[seg + 1];
  const int nt = (kve - kvb + 63) >> 6;
  const int fr = l & 15, fg = (l >> 4) * 8;
  const int row0 = qblk + wq * 64;

  // Q fragments for 4 subtiles (B-operand of swapped QK^T; q pre-scaled)
  const f16* qb = qh + ((size_t)h * SEQ + row0 + fr) * DP + fg;
  f16x8 aq[4][3];
#pragma unroll
  for (int u = 0; u < 4; u++)
#pragma unroll
    for (int kk = 0; kk < 3; kk++)
      aq[u][kk] = *(const f16x8*)(qb + u * 16 * DP + kk * 32);

  // staging decode: K = 768 chunks (2 grp x 32 r x 12 c), V = 640 (2 x 80 x 4)
  const int k0g = tid / 384, k0r = (tid % 384) / 12, k0c = tid % 12;
  const int k1r = (128 + tid) / 12, k1c = (128 + tid) % 12;       // chunk 512+tid, grp1
  const int v0g = tid / 320, v0r = (tid % 320) / 4, v0c = tid & 3;
  const int v1r = (192 + tid) >> 2, v1c = (192 + tid) & 3;        // chunk 512+tid, grp1
  const f16* kp0 = kh + ((size_t)h * SEQ + kvb + k0g * 32 + k0r) * DP + k0c * 8;
  const f16* kp1 = kh + ((size_t)h * SEQ + kvb + 32 + k1r) * DP + k1c * 8;
  const f16* vp0 = vt + ((size_t)h * HD + v0r) * SEQ + kvb + v0g * 32 + v0c * 8;
  const f16* vp1 = vt + ((size_t)h * HD + v1r) * SEQ + kvb + 32 + v1c * 8;
  const int dK0 = k0g * KSZ + k0r * 104 + k0c * 8;
  const int dK1 = KSZ + k1r * 104 + k1c * 8;
  const int dV0 = 2 * KSZ + v0g * VSZ + v0r * 56 + v0c * 8;
  const int dV1 = 2 * KSZ + VSZ + v1r * 56 + v1c * 8;

  float m = -1e30f;
  float ls[4] = {0.f, 0.f, 0.f, 0.f};
  f32x4 o[4][5] = {};

  // prologue: load tile 0 -> regs -> buf 0
  uint4 rk0, rk1, rv0, rv1;
  rk0 = *(const uint4*)kp0;
  if (tid < 256) rk1 = *(const uint4*)kp1;
  rv0 = *(const uint4*)vp0;
  if (tid < 128) rv1 = *(const uint4*)vp1;
  *(uint4*)(smem + dK0) = rk0;
  if (tid < 256) *(uint4*)(smem + dK1) = rk1;
  *(uint4*)(smem + dV0) = rv0;
  if (tid < 128) *(uint4*)(smem + dV1) = rv1;
  __syncthreads();

  for (int t = 0; t < nt; t++) {
    const int p = t & 1;
    const int off = (t + 1) * 64;            // next-tile offset
    const bool more = (t + 1 < nt);

    if (more) {                              // issue next-tile loads (T14: early)
      rk0 = *(const uint4*)(kp0 + (size_t)off * DP);
      if (tid < 256) rk1 = *(const uint4*)(kp1 + (size_t)off * DP);
      rv0 = *(const uint4*)(vp0 + off);
      if (tid < 128) rv1 = *(const uint4*)(vp1 + off);
    }

    // compute from buf p (my grp's tiles)
    const f16* myK = smem + p * HSZ + grp * KSZ;
    const f16* myV = smem + p * HSZ + 2 * KSZ + grp * VSZ;

    f32x4 s[4][2] = {};
    __builtin_amdgcn_s_setprio(1);
#pragma unroll
    for (int kk = 0; kk < 3; kk++) {
      const f16x8 k0 = *(const f16x8*)(myK + fr * 104 + kk * 32 + fg);
      const f16x8 k1 = *(const f16x8*)(myK + (16 + fr) * 104 + kk * 32 + fg);
#pragma unroll
      for (int u = 0; u < 4; u++) {
        s[u][0] = __builtin_amdgcn_mfma_f32_16x16x32_f16(k0, aq[u][kk], s[u][0], 0, 0, 0);
        s[u][1] = __builtin_amdgcn_mfma_f32_16x16x32_f16(k1, aq[u][kk], s[u][1], 0, 0, 0);
      }
    }
    __builtin_amdgcn_s_setprio(0);

    // per-lane max + wave vote; full reduce + rescale only when needed (rare)
    float pmax = s[0][0][0];
#pragma unroll
    for (int u = 0; u < 4; u++)
#pragma unroll
      for (int j = 0; j < 4; j++)
        pmax = fmaxf(pmax, fmaxf(s[u][0][j], s[u][1][j]));
    if (__any(pmax > m + 8.f)) {
      float tmax = pmax;
      tmax = fmaxf(tmax, __shfl_xor(tmax, 1));
      tmax = fmaxf(tmax, __shfl_xor(tmax, 2));
      tmax = fmaxf(tmax, __shfl_xor(tmax, 4));
      tmax = fmaxf(tmax, __shfl_xor(tmax, 8));
      tmax = fmaxf(tmax, __shfl_xor(tmax, 16));
      tmax = fmaxf(tmax, __shfl_xor(tmax, 32));
      const float aa = __builtin_amdgcn_exp2f(m - tmax);
      m = tmax;
#pragma unroll
      for (int u = 0; u < 4; u++) {
        ls[u] *= aa;
#pragma unroll
        for (int dt = 0; dt < 5; dt++)
#pragma unroll
          for (int j = 0; j < 4; j++) o[u][dt][j] *= aa;
      }
    }

    // P = exp2(S - m) in-place, accumulate row sums, pack to PV A-fragments
    f16x8 pa[4];
#pragma unroll
    for (int u = 0; u < 4; u++) {
#pragma unroll
      for (int r = 0; r < 4; r++) {
        s[u][0][r] = __builtin_amdgcn_exp2f(s[u][0][r] - m);
        s[u][1][r] = __builtin_amdgcn_exp2f(s[u][1][r] - m);
        ls[u] += s[u][0][r] + s[u][1][r];
      }
      uint4 ua;
      ua.x = pk2(s[u][0][0], s[u][0][1]); ua.y = pk2(s[u][0][2], s[u][0][3]);
      ua.z = pk2(s[u][1][0], s[u][1][1]); ua.w = pk2(s[u][1][2], s[u][1][3]);
      pa[u] = bc16(ua);
    }

    __builtin_amdgcn_s_setprio(1);
#pragma unroll
    for (int dt = 0; dt < 5; dt++) {
      const f16x8 bv = *(const f16x8*)(myV + (dt * 16 + fr) * 56 + fg);
#pragma unroll
      for (int u = 0; u < 4; u++)
        o[u][dt] = __builtin_amdgcn_mfma_f32_16x16x32_f16(pa[u], bv, o[u][dt], 0, 0, 0);
    }
    __builtin_amdgcn_s_setprio(0);

    if (more) {                              // write next tile (T14: late)
      f16* dst = smem + (1 - p) * HSZ;
      *(uint4*)(dst + dK0) = rk0;
      if (tid < 256) *(uint4*)(dst + dK1) = rk1;
      *(uint4*)(dst + dV0) = rv0;
      if (tid < 128) *(uint4*)(dst + dV1) = rv1;
    }
    __syncthreads();                         // single barrier per iteration
  }

  // finish per-subtile row sums (partials spread across g = l>>4)
#pragma unroll
  for (int u = 0; u < 4; u++) {
    ls[u] += __shfl_xor(ls[u], 16);
    ls[u] += __shfl_xor(ls[u], 32);
  }

  // merge kv-halves in 2 phases (subtiles 0,1 then 2,3); 44 KB merge buf
  float* mb = (float*)smem;
  float aA = 1.f, aB = 0.f;
  if (grp == 1) {
    float* dst = mb + (wq * 64 + l) * 43;
    dst[0] = m; dst[1] = ls[0]; dst[2] = ls[1];
#pragma unroll
    for (int u = 0; u < 2; u++)
#pragma unroll
      for (int dt = 0; dt < 5; dt++)
#pragma unroll
        for (int j = 0; j < 4; j++)
          dst[3 + u * 20 + dt * 4 + j] = o[u][dt][j];
  }
  __syncthreads();
  if (grp == 0) {
    const float* src = mb + (wq * 64 + l) * 43;
    const float mB = src[0];
    const float M = fmaxf(m, mB);
    aA = __builtin_amdgcn_exp2f(m - M);
    aB = __builtin_amdgcn_exp2f(mB - M);
    ls[0] = ls[0] * aA + src[1] * aB;
    ls[1] = ls[1] * aA + src[2] * aB;
#pragma unroll
    for (int u = 0; u < 2; u++)
#pragma unroll
      for (int dt = 0; dt < 5; dt++)
#pragma unroll
        for (int j = 0; j < 4; j++)
          o[u][dt][j] = o[u][dt][j] * aA + src[3 + u * 20 + dt * 4 + j] * aB;
  }
  __syncthreads();
  if (grp == 1) {
    float* dst = mb + (wq * 64 + l) * 42;
    dst[0] = ls[2]; dst[1] = ls[3];
#pragma unroll
    for (int u = 2; u < 4; u++)
#pragma unroll
      for (int dt = 0; dt < 5; dt++)
#pragma unroll
        for (int j = 0; j < 4; j++)
          dst[2 + (u - 2) * 20 + dt * 4 + j] = o[u][dt][j];
  }
  __syncthreads();
  if (grp == 0) {
    const float* src = mb + (wq * 64 + l) * 42;
    ls[2] = ls[2] * aA + src[0] * aB;
    ls[3] = ls[3] * aA + src[1] * aB;
#pragma unroll
    for (int u = 2; u < 4; u++)
#pragma unroll
      for (int dt = 0; dt < 5; dt++)
#pragma unroll
        for (int j = 0; j < 4; j++)
          o[u][dt][j] = o[u][dt][j] * aA + src[2 + (u - 2) * 20 + dt * 4 + j] * aB;

    // redistribute 1/rowsum (indexed by q=l&15) to o-rows (q'=4*(l>>4)+j)
#pragma unroll
    for (int u = 0; u < 4; u++) {
      const float inv = 1.0f / ls[u];
      float iv[4];
#pragma unroll
      for (int j = 0; j < 4; j++) {
        const int srcl = (l & 48) | ((l >> 4) * 4 + j);
        iv[j] = __shfl(inv, srcl);
      }
      const int orow = row0 + u * 16 + (l >> 4) * 4;
#pragma unroll
      for (int dt = 0; dt < 5; dt++)
#pragma unroll
        for (int j = 0; j < 4; j++)
          ao[(size_t)(orow + j) * HIDN + h * HD + dt * 16 + fr] = (f16)(o[u][dt][j] * iv[j]);
    }
  }
}

extern "C" void kernel_launch(void* const* d_in, const int* in_sizes, int n_in,
                              void* d_out, int out_size, void* d_ws, size_t ws_size,
                              hipStream_t stream) {
  const float* x      = (const float*)d_in[0];
  const int*   cu     = (const int*)d_in[1];
  const float* rpe    = (const float*)d_in[2];
  const float* qkv_w  = (const float*)d_in[3];
  const float* qkv_b  = (const float*)d_in[4];
  const float* proj_w = (const float*)d_in[5];
  const float* proj_b = (const float*)d_in[6];

  char* ws = (char*)d_ws;
  f16* xb    = (f16*)(ws);              // [4096][1280]
  f16* wqkv  = (f16*)(ws + 10485760);   // [3840][1280]
  f16* wproj = (f16*)(ws + 20316160);   // [1280][1280]
  f16* qkvb  = (f16*)(ws + 23592960);   // [4096][3840]
  f16* qh    = (f16*)(ws + 55050240);   // [16][4096][96]
  f16* kh    = (f16*)(ws + 67633152);   // [16][4096][96]
  f16* vt    = (f16*)(ws + 80216064);   // [16][80][4096] (kv-permuted)
  f16* ao    = xb;

  const int n0 = SEQ * HIDN, n1 = 3 * HIDN * HIDN, n2 = HIDN * HIDN;
  cvt3_kernel<<<(n0 + n1 + n2) / (256 * 8), 256, 0, stream>>>(
      x, qkv_w, proj_w, xb, wqkv, wproj, n0, n1, n2);

  qkv_gemm8<<<240, 512, 0, stream>>>(xb, wqkv, qkv_b, qkvb);

  prep_kernel<<<RPB + 1024, 256, 0, stream>>>(qkvb, rpe, qh, kh, vt);

  attn_kernel<<<256, 512, 0, stream>>>(qh, kh, vt, cu, ao);

  // proj: 320 blocks = 8 XCD x 40, nbx = 1280/128 = 10
  gemm_bt64<1><<<320, 256, 0, stream>>>(
      ao, wproj, proj_b, d_out, SEQ, HIDN, HIDN, 10, 40);
}

// Round 15
// 130.681 us; speedup vs baseline: 3.6699x; 1.0130x over previous
//
#include <hip/hip_runtime.h>

typedef _Float16 f16;
typedef __attribute__((ext_vector_type(8))) _Float16 f16x8;
typedef __attribute__((ext_vector_type(4))) float f32x4;

#define SEQ   4096
#define NH    16
#define HD    80
#define HIDN  1280
#define DP    96

// attn LDS geometry (R8-proven)
#define KSZ   3328          // 32 rows x 104 (padded) f16
#define VSZ   4480          // 80 rows x 56 (padded) f16
#define HSZ   (2*KSZ + 2*VSZ)   // one double-buffer half: 15616 f16 = 31,232 B

// 8-phase GEMM constants (QKV: M=4096, N=3840, K=1280)
#define KQ   1280
#define NQ   3840
#define NIT  10      // K / 128

__device__ __forceinline__ void gload16(const void* g, void* l) {
  __builtin_amdgcn_global_load_lds(
      (const __attribute__((address_space(1))) unsigned int*)g,
      (__attribute__((address_space(3))) unsigned int*)l, 16, 0, 0);
}

__device__ __forceinline__ unsigned pk2(float a, float b) {
  return __builtin_bit_cast(unsigned, __builtin_amdgcn_cvt_pkrtz(a, b));
}
__device__ __forceinline__ f16x8 bc16(uint4 u) { return __builtin_bit_cast(f16x8, u); }

#define BAR() __builtin_amdgcn_s_barrier()
#define VMCNT(n) do { asm volatile("s_waitcnt vmcnt(" #n ")" ::: "memory"); \
                      __builtin_amdgcn_sched_barrier(0); } while (0)
#define STG(Lb, g, buf, h, kt)                                                  \
  do {                                                                          \
    gload16((g) + (size_t)((h) * 128) * KQ + (kt) * 64,                         \
            (Lb) + (buf) * 16384 + ((h) * 128) * 64 + w * 512);                 \
    gload16((g) + (size_t)((h) * 128 + 64) * KQ + (kt) * 64,                    \
            (Lb) + (buf) * 16384 + ((h) * 128 + 64) * 64 + w * 512);            \
  } while (0)
#define MFQ(IOFF, JOFF, BB)                                                     \
  do {                                                                          \
    __builtin_amdgcn_s_setprio(1);                                              \
    _Pragma("unroll")                                                           \
    for (int i_ = 0; i_ < 4; i_++)                                              \
      _Pragma("unroll")                                                         \
      for (int j_ = 0; j_ < 2; j_++)                                            \
        _Pragma("unroll")                                                       \
        for (int s_ = 0; s_ < 2; s_++)                                          \
          acc[i_ + IOFF][j_ + JOFF] = __builtin_amdgcn_mfma_f32_16x16x32_f16(   \
              a[i_][s_], BB[j_][s_], acc[i_ + IOFF][j_ + JOFF], 0, 0, 0);       \
    __builtin_amdgcn_s_setprio(0);                                              \
  } while (0)

// ---------------- fused f32 -> f16 convert for x, qkv_w, proj_w ----------------
__global__ __launch_bounds__(256) void cvt3_kernel(const float* __restrict__ s0,
                                                   const float* __restrict__ s1,
                                                   const float* __restrict__ s2,
                                                   f16* __restrict__ d0,
                                                   f16* __restrict__ d1,
                                                   f16* __restrict__ d2,
                                                   int n0, int n1, int n2) {
  long i = (long)(blockIdx.x * 256 + threadIdx.x) * 8;
  const float* s; f16* d;
  if (i < n0)                { s = s0 + i;            d = d0 + i; }
  else if (i < n0 + n1)      { s = s1 + (i - n0);     d = d1 + (i - n0); }
  else if (i < n0 + n1 + n2) { s = s2 + (i - n0 - n1); d = d2 + (i - n0 - n1); }
  else return;
  f32x4 v0 = *(const f32x4*)(s);
  f32x4 v1 = *(const f32x4*)(s + 4);
  f16x8 o;
#pragma unroll
  for (int j = 0; j < 4; j++) { o[j] = (f16)v0[j]; o[4 + j] = (f16)v1[j]; }
  *(f16x8*)(d) = o;
}

// ---------------- 8-phase 256^2 GEMM: C[4096][3840] = A * B^T + bias (f16 out) ----
// R12-proven schedule. NEW: 2-D compact XCD regions (~5x6 tiles) so each XCD's
// A+B working set is ~7.2 MB with 5-6 concurrent readers per B-panel (vs 2x15
// rows: 11.1 MB, 2 readers) -> higher L2 hit rate on panel re-reads.
__global__ __launch_bounds__(512, 2) void qkv_gemm8(const f16* __restrict__ A,
                                                    const f16* __restrict__ B,
                                                    const float* __restrict__ bias,
                                                    f16* __restrict__ C) {
  __shared__ __align__(16) f16 LA[2 * 16384];
  __shared__ __align__(16) f16 LB[2 * 16384];
  const int tid = threadIdx.x, w = tid >> 6, l = tid & 63;
  // 240 blocks = 8 XCD x 30 slots (HW: blockIdx -> XCD round-robin by &7)
  const int xcd = blockIdx.x & 7, slot = blockIdx.x >> 3;
  int by, bx;
  if (xcd < 6)      { by = (xcd >> 1) * 5 + slot / 6; bx = (xcd & 1) * 6 + slot % 6; }
  else if (xcd == 6){ by = slot / 3;                  bx = 12 + slot % 3; }
  else {
    if (slot < 15)  { by = 10 + slot / 3;             bx = 12 + slot % 3; }
    else            { by = 15;                        bx = slot - 15; }
  }
  const int m0 = by * 256, n0 = bx * 256;
  const int wm = (w >> 2) * 128, wn = (w & 3) * 64;
  const int fr = l & 15, fq = l >> 4;
  const int rx = fr & 7;
  const int cA0 = (fq ^ rx) * 8;
  const int cA1 = ((4 + fq) ^ rx) * 8;

  const int srow = w * 8 + (l >> 3);
  const int scol = ((l & 7) ^ (l >> 3)) * 8;
  const f16* gA = A + (size_t)(m0 + srow) * KQ + scol;
  const f16* gB = B + (size_t)(n0 + srow) * KQ + scol;

  f32x4 acc[8][4] = {};
  f16x8 a[4][2], b0[2][2], b1[2][2];

  STG(LA, gA, 0, 0, 0); STG(LA, gA, 0, 1, 0);
  STG(LB, gB, 0, 0, 0); STG(LB, gB, 0, 1, 0);
  STG(LB, gB, 1, 0, 1); STG(LB, gB, 1, 1, 1);
  VMCNT(4);
  BAR();

  for (int it = 0; it < NIT; ++it) {
    const int t = 2 * it;
    const bool lastit = (it == NIT - 1);

#pragma unroll
    for (int i = 0; i < 4; i++) {
      a[i][0] = *(const f16x8*)(LA + (wm + i * 16 + fr) * 64 + cA0);
      a[i][1] = *(const f16x8*)(LA + (wm + i * 16 + fr) * 64 + cA1);
    }
#pragma unroll
    for (int j = 0; j < 2; j++) {
      b0[j][0] = *(const f16x8*)(LB + (wn + j * 16 + fr) * 64 + cA0);
      b0[j][1] = *(const f16x8*)(LB + (wn + j * 16 + fr) * 64 + cA1);
    }
    STG(LA, gA, 1, 0, t + 1);
    BAR(); MFQ(0, 0, b0); BAR();

#pragma unroll
    for (int j = 0; j < 2; j++) {
      b1[j][0] = *(const f16x8*)(LB + (wn + 32 + j * 16 + fr) * 64 + cA0);
      b1[j][1] = *(const f16x8*)(LB + (wn + 32 + j * 16 + fr) * 64 + cA1);
    }
    STG(LA, gA, 1, 1, t + 1);
    BAR(); MFQ(0, 2, b1); BAR();

#pragma unroll
    for (int i = 0; i < 4; i++) {
      a[i][0] = *(const f16x8*)(LA + (wm + 64 + i * 16 + fr) * 64 + cA0);
      a[i][1] = *(const f16x8*)(LA + (wm + 64 + i * 16 + fr) * 64 + cA1);
    }
    if (!lastit) { STG(LB, gB, 0, 0, t + 2); }
    BAR(); MFQ(4, 0, b0); BAR();

    if (!lastit) { STG(LB, gB, 0, 1, t + 2); VMCNT(4); }
    else         { VMCNT(0); }
    BAR(); MFQ(4, 2, b1); BAR();

#pragma unroll
    for (int i = 0; i < 4; i++) {
      a[i][0] = *(const f16x8*)(LA + 16384 + (wm + i * 16 + fr) * 64 + cA0);
      a[i][1] = *(const f16x8*)(LA + 16384 + (wm + i * 16 + fr) * 64 + cA1);
    }
#pragma unroll
    for (int j = 0; j < 2; j++) {
      b0[j][0] = *(const f16x8*)(LB + 16384 + (wn + j * 16 + fr) * 64 + cA0);
      b0[j][1] = *(const f16x8*)(LB + 16384 + (wn + j * 16 + fr) * 64 + cA1);
    }
    if (!lastit) { STG(LA, gA, 0, 0, t + 2); }
    BAR(); MFQ(0, 0, b0); BAR();

#pragma unroll
    for (int j = 0; j < 2; j++) {
      b1[j][0] = *(const f16x8*)(LB + 16384 + (wn + 32 + j * 16 + fr) * 64 + cA0);
      b1[j][1] = *(const f16x8*)(LB + 16384 + (wn + 32 + j * 16 + fr) * 64 + cA1);
    }
    if (!lastit) { STG(LA, gA, 0, 1, t + 2); }
    BAR(); MFQ(0, 2, b1); BAR();

#pragma unroll
    for (int i = 0; i < 4; i++) {
      a[i][0] = *(const f16x8*)(LA + 16384 + (wm + 64 + i * 16 + fr) * 64 + cA0);
      a[i][1] = *(const f16x8*)(LA + 16384 + (wm + 64 + i * 16 + fr) * 64 + cA1);
    }
    if (!lastit) { STG(LB, gB, 1, 0, t + 3); }
    BAR(); MFQ(4, 0, b0); BAR();

    if (!lastit) { STG(LB, gB, 1, 1, t + 3); VMCNT(4); }
    BAR(); MFQ(4, 2, b1); BAR();
  }

#pragma unroll
  for (int i = 0; i < 8; i++) {
    const int row = m0 + wm + i * 16 + fq * 4;
#pragma unroll
    for (int j = 0; j < 4; j++) {
      const int col = n0 + wn + j * 16 + fr;
      const float bv = bias[col];
#pragma unroll
      for (int q = 0; q < 4; q++)
        C[(size_t)(row + q) * NQ + col] = (f16)(acc[i][j][q] + bv);
    }
  }
}

// ---------------- 128^2 GEMM, BK=64, two stride-32 sub-buffers (proj) ----------
template<int OUT_F32>
__global__ __launch_bounds__(256) void gemm_bt64(const f16* __restrict__ A,
                                                 const f16* __restrict__ B,
                                                 const float* __restrict__ bias,
                                                 void* __restrict__ C,
                                                 int M, int N, int K,
                                                 int nbx, int cpx) {
  __shared__ __align__(16) f16 AsF[8192];   // [2 sub][128][32]
  __shared__ __align__(16) f16 BsF[8192];
  const int tid = threadIdx.x;
  const int w = tid >> 6, l = tid & 63;
  const int bid = (blockIdx.x & 7) * cpx + (blockIdx.x >> 3);
  const int m0 = (bid / nbx) * 128, n0 = (bid % nbx) * 128;
  const int wm = (w >> 1) * 64, wn = (w & 1) * 64;
  const int fr = l & 15, fg = (l >> 4) * 8;

  size_t aoff[4], boff[4];
#pragma unroll
  for (int i = 0; i < 4; i++) {
    const int d = i * 256 + tid;
    const int sub = d >> 9, dd = d & 511;
    const int r = dd >> 2, c = (dd & 3) + sub * 4;
    aoff[i] = (size_t)(m0 + r) * K + c * 8;
    boff[i] = (size_t)(n0 + r) * K + c * 8;
  }

  f32x4 acc[4][4] = {};

  for (int k0 = 0; k0 < K; k0 += 64) {
    if (k0) __syncthreads();
#pragma unroll
    for (int i = 0; i < 4; i++) gload16(A + aoff[i] + k0, AsF + (i * 256 + tid) * 8);
#pragma unroll
    for (int i = 0; i < 4; i++) gload16(B + boff[i] + k0, BsF + (i * 256 + tid) * 8);
    __syncthreads();
    f16x8 af[4][2], bf[4][2];
#pragma unroll
    for (int i = 0; i < 4; i++)
#pragma unroll
      for (int s = 0; s < 2; s++) {
        af[i][s] = *(const f16x8*)(AsF + s * 4096 + (wm + i * 16 + fr) * 32 + fg);
        bf[i][s] = *(const f16x8*)(BsF + s * 4096 + (wn + i * 16 + fr) * 32 + fg);
      }
#pragma unroll
    for (int i = 0; i < 4; i++)
#pragma unroll
      for (int j = 0; j < 4; j++)
#pragma unroll
        for (int s = 0; s < 2; s++)
          acc[i][j] = __builtin_amdgcn_mfma_f32_16x16x32_f16(af[i][s], bf[j][s], acc[i][j], 0, 0, 0);
  }

  const int q4 = (l >> 4) * 4;
#pragma unroll
  for (int i = 0; i < 4; i++) {
    const int row = m0 + wm + i * 16 + q4;
#pragma unroll
    for (int j = 0; j < 4; j++) {
      const int col = n0 + wn + j * 16 + fr;
      const float bv = bias[col];
#pragma unroll
      for (int q = 0; q < 4; q++) {
        float v = acc[i][j][q] + bv;
        if (OUT_F32) ((float*)C)[(size_t)(row + q) * N + col] = v;
        else         ((f16*)C)[(size_t)(row + q) * N + col] = (f16)v;
      }
    }
  }
}

// ---------------- prep: fused vectorized RoPE + V transpose --------------------
#define RPB 1280
__global__ __launch_bounds__(256) void prep_kernel(const f16* __restrict__ qkvb,
                                                   const float* __restrict__ rpe,
                                                   f16* __restrict__ qh,
                                                   f16* __restrict__ kh,
                                                   f16* __restrict__ vt) {
  __shared__ f16 tile[HD][65];
  const int b = blockIdx.x;
  if (b < RPB) {
    const float SCLT = 0.1118033988749895f * 1.4426950408889634f;  // 1/sqrt(80)*log2e
    const int t = b * 256 + threadIdx.x;          // < SEQ*NH*5
    const int d8 = (t % 5) * 8;
    const int h = (t / 5) % NH;
    const int s = t / (5 * NH);
    const f32x4 f0 = *(const f32x4*)(rpe + s * 40 + d8);
    const f32x4 f1 = *(const f32x4*)(rpe + s * 40 + d8 + 4);
    const f16* base = qkvb + (size_t)s * (3 * HIDN) + h * HD;
    const f16x8 q0 = *(const f16x8*)(base + d8);
    const f16x8 q1 = *(const f16x8*)(base + 40 + d8);
    const f16x8 k0 = *(const f16x8*)(base + HIDN + d8);
    const f16x8 k1 = *(const f16x8*)(base + HIDN + 40 + d8);
    f16x8 oq0, oq1, ok0, ok1;
#pragma unroll
    for (int j = 0; j < 8; j++) {
      const float fv = (j < 4) ? f0[j] : f1[j - 4];
      float sn, cs;
      __sincosf(fv, &sn, &cs);
      const float a = (float)q0[j], bq = (float)q1[j];
      oq0[j] = (f16)((a * cs - bq * sn) * SCLT);
      oq1[j] = (f16)((bq * cs + a * sn) * SCLT);
      const float ka = (float)k0[j], kb = (float)k1[j];
      ok0[j] = (f16)(ka * cs - kb * sn);
      ok1[j] = (f16)(kb * cs + ka * sn);
    }
    const size_t ob = ((size_t)h * SEQ + s) * DP;
    *(f16x8*)(qh + ob + d8)      = oq0;
    *(f16x8*)(qh + ob + 40 + d8) = oq1;
    *(f16x8*)(kh + ob + d8)      = ok0;
    *(f16x8*)(kh + ob + 40 + d8) = ok1;
    if (d8 == 32) {      // zero the [80,96) pad
      const f16x8 z = {};
      *(f16x8*)(qh + ob + 80) = z; *(f16x8*)(qh + ob + 88) = z;
      *(f16x8*)(kh + ob + 80) = z; *(f16x8*)(kh + ob + 88) = z;
    }
  } else {
    const int bb = b - RPB;
    const int h = bb >> 6;
    const int s0 = (bb & 63) * 64;
    for (int idx = threadIdx.x; idx < 64 * HD; idx += 256) {
      const int sr = idx / HD, d = idx % HD;
      tile[d][sr] = qkvb[(size_t)(s0 + sr) * (3 * HIDN) + 2 * HIDN + h * HD + d];
    }
    __syncthreads();
    // kv-permuted within 32-blocks: slot s -> actual kv matches MFMA k-slot order
    for (int idx = threadIdx.x; idx < HD * 64; idx += 256) {
      const int d = idx >> 6, sc = idx & 63;
      const int blk = sc >> 5, s = sc & 31, g = s >> 3, j = s & 7;
      const int act = blk * 32 + ((j < 4) ? (4 * g + j) : (16 + 4 * g + (j - 4)));
      vt[((size_t)h * HD + d) * SEQ + s0 + sc] = tile[d][act];
    }
  }
}

// ---------------- Flash attention: QBLK=256, 64 q-rows/wave (R12-proven) -------
__global__ __launch_bounds__(512, 2) void attn_kernel(const f16* __restrict__ qh,
                                                      const f16* __restrict__ kh,
                                                      const f16* __restrict__ vt,
                                                      const int* __restrict__ cu,
                                                      f16* __restrict__ ao) {
  __shared__ __align__(16) f16 smem[2 * HSZ];        // 62,464 B
  const int tid = threadIdx.x, w = tid >> 6, l = tid & 63;
  const int grp = w >> 2, wq = w & 3;
  const int bid = blockIdx.x;
  const int g = bid & 63, ib = bid >> 6;             // ib in 0..3
  const int h = g >> 2;
  const int qblk = ((g & 3) * 4 + ib) * 256;
  int seg = 0;
  while (cu[seg + 1] <= qblk) seg++;
  const int kvb = cu[seg], kve = cu[seg + 1];
  const int nt = (kve - kvb + 63) >> 6;
  const int fr = l & 15, fg = (l >> 4) * 8;
  const int row0 = qblk + wq * 64;

  // Q fragments for 4 subtiles (B-operand of swapped QK^T; q pre-scaled)
  const f16* qb = qh + ((size_t)h * SEQ + row0 + fr) * DP + fg;
  f16x8 aq[4][3];
#pragma unroll
  for (int u = 0; u < 4; u++)
#pragma unroll
    for (int kk = 0; kk < 3; kk++)
      aq[u][kk] = *(const f16x8*)(qb + u * 16 * DP + kk * 32);

  // staging decode: K = 768 chunks (2 grp x 32 r x 12 c), V = 640 (2 x 80 x 4)
  const int k0g = tid / 384, k0r = (tid % 384) / 12, k0c = tid % 12;
  const int k1r = (128 + tid) / 12, k1c = (128 + tid) % 12;       // chunk 512+tid, grp1
  const int v0g = tid / 320, v0r = (tid % 320) / 4, v0c = tid & 3;
  const int v1r = (192 + tid) >> 2, v1c = (192 + tid) & 3;        // chunk 512+tid, grp1
  const f16* kp0 = kh + ((size_t)h * SEQ + kvb + k0g * 32 + k0r) * DP + k0c * 8;
  const f16* kp1 = kh + ((size_t)h * SEQ + kvb + 32 + k1r) * DP + k1c * 8;
  const f16* vp0 = vt + ((size_t)h * HD + v0r) * SEQ + kvb + v0g * 32 + v0c * 8;
  const f16* vp1 = vt + ((size_t)h * HD + v1r) * SEQ + kvb + 32 + v1c * 8;
  const int dK0 = k0g * KSZ + k0r * 104 + k0c * 8;
  const int dK1 = KSZ + k1r * 104 + k1c * 8;
  const int dV0 = 2 * KSZ + v0g * VSZ + v0r * 56 + v0c * 8;
  const int dV1 = 2 * KSZ + VSZ + v1r * 56 + v1c * 8;

  float m = -1e30f;
  float ls[4] = {0.f, 0.f, 0.f, 0.f};
  f32x4 o[4][5] = {};

  // prologue: load tile 0 -> regs -> buf 0
  uint4 rk0, rk1, rv0, rv1;
  rk0 = *(const uint4*)kp0;
  if (tid < 256) rk1 = *(const uint4*)kp1;
  rv0 = *(const uint4*)vp0;
  if (tid < 128) rv1 = *(const uint4*)vp1;
  *(uint4*)(smem + dK0) = rk0;
  if (tid < 256) *(uint4*)(smem + dK1) = rk1;
  *(uint4*)(smem + dV0) = rv0;
  if (tid < 128) *(uint4*)(smem + dV1) = rv1;
  __syncthreads();

  for (int t = 0; t < nt; t++) {
    const int p = t & 1;
    const int off = (t + 1) * 64;            // next-tile offset
    const bool more = (t + 1 < nt);

    if (more) {                              // issue next-tile loads (T14: early)
      rk0 = *(const uint4*)(kp0 + (size_t)off * DP);
      if (tid < 256) rk1 = *(const uint4*)(kp1 + (size_t)off * DP);
      rv0 = *(const uint4*)(vp0 + off);
      if (tid < 128) rv1 = *(const uint4*)(vp1 + off);
    }

    // compute from buf p (my grp's tiles)
    const f16* myK = smem + p * HSZ + grp * KSZ;
    const f16* myV = smem + p * HSZ + 2 * KSZ + grp * VSZ;

    f32x4 s[4][2] = {};
    __builtin_amdgcn_s_setprio(1);
#pragma unroll
    for (int kk = 0; kk < 3; kk++) {
      const f16x8 k0 = *(const f16x8*)(myK + fr * 104 + kk * 32 + fg);
      const f16x8 k1 = *(const f16x8*)(myK + (16 + fr) * 104 + kk * 32 + fg);
#pragma unroll
      for (int u = 0; u < 4; u++) {
        s[u][0] = __builtin_amdgcn_mfma_f32_16x16x32_f16(k0, aq[u][kk], s[u][0], 0, 0, 0);
        s[u][1] = __builtin_amdgcn_mfma_f32_16x16x32_f16(k1, aq[u][kk], s[u][1], 0, 0, 0);
      }
    }
    __builtin_amdgcn_s_setprio(0);

    // per-lane max + wave vote; full reduce + rescale only when needed (rare)
    float pmax = s[0][0][0];
#pragma unroll
    for (int u = 0; u < 4; u++)
#pragma unroll
      for (int j = 0; j < 4; j++)
        pmax = fmaxf(pmax, fmaxf(s[u][0][j], s[u][1][j]));
    if (__any(pmax > m + 8.f)) {
      float tmax = pmax;
      tmax = fmaxf(tmax, __shfl_xor(tmax, 1));
      tmax = fmaxf(tmax, __shfl_xor(tmax, 2));
      tmax = fmaxf(tmax, __shfl_xor(tmax, 4));
      tmax = fmaxf(tmax, __shfl_xor(tmax, 8));
      tmax = fmaxf(tmax, __shfl_xor(tmax, 16));
      tmax = fmaxf(tmax, __shfl_xor(tmax, 32));
      const float aa = __builtin_amdgcn_exp2f(m - tmax);
      m = tmax;
#pragma unroll
      for (int u = 0; u < 4; u++) {
        ls[u] *= aa;
#pragma unroll
        for (int dt = 0; dt < 5; dt++)
#pragma unroll
          for (int j = 0; j < 4; j++) o[u][dt][j] *= aa;
      }
    }

    // P = exp2(S - m) in-place, accumulate row sums, pack to PV A-fragments
    f16x8 pa[4];
#pragma unroll
    for (int u = 0; u < 4; u++) {
#pragma unroll
      for (int r = 0; r < 4; r++) {
        s[u][0][r] = __builtin_amdgcn_exp2f(s[u][0][r] - m);
        s[u][1][r] = __builtin_amdgcn_exp2f(s[u][1][r] - m);
        ls[u] += s[u][0][r] + s[u][1][r];
      }
      uint4 ua;
      ua.x = pk2(s[u][0][0], s[u][0][1]); ua.y = pk2(s[u][0][2], s[u][0][3]);
      ua.z = pk2(s[u][1][0], s[u][1][1]); ua.w = pk2(s[u][1][2], s[u][1][3]);
      pa[u] = bc16(ua);
    }

    __builtin_amdgcn_s_setprio(1);
#pragma unroll
    for (int dt = 0; dt < 5; dt++) {
      const f16x8 bv = *(const f16x8*)(myV + (dt * 16 + fr) * 56 + fg);
#pragma unroll
      for (int u = 0; u < 4; u++)
        o[u][dt] = __builtin_amdgcn_mfma_f32_16x16x32_f16(pa[u], bv, o[u][dt], 0, 0, 0);
    }
    __builtin_amdgcn_s_setprio(0);

    if (more) {                              // write next tile (T14: late)
      f16* dst = smem + (1 - p) * HSZ;
      *(uint4*)(dst + dK0) = rk0;
      if (tid < 256) *(uint4*)(dst + dK1) = rk1;
      *(uint4*)(dst + dV0) = rv0;
      if (tid < 128) *(uint4*)(dst + dV1) = rv1;
    }
    __syncthreads();                         // single barrier per iteration
  }

  // finish per-subtile row sums (partials spread across g = l>>4)
#pragma unroll
  for (int u = 0; u < 4; u++) {
    ls[u] += __shfl_xor(ls[u], 16);
    ls[u] += __shfl_xor(ls[u], 32);
  }

  // merge kv-halves in 2 phases (subtiles 0,1 then 2,3); 44 KB merge buf
  float* mb = (float*)smem;
  float aA = 1.f, aB = 0.f;
  if (grp == 1) {
    float* dst = mb + (wq * 64 + l) * 43;
    dst[0] = m; dst[1] = ls[0]; dst[2] = ls[1];
#pragma unroll
    for (int u = 0; u < 2; u++)
#pragma unroll
      for (int dt = 0; dt < 5; dt++)
#pragma unroll
        for (int j = 0; j < 4; j++)
          dst[3 + u * 20 + dt * 4 + j] = o[u][dt][j];
  }
  __syncthreads();
  if (grp == 0) {
    const float* src = mb + (wq * 64 + l) * 43;
    const float mB = src[0];
    const float M = fmaxf(m, mB);
    aA = __builtin_amdgcn_exp2f(m - M);
    aB = __builtin_amdgcn_exp2f(mB - M);
    ls[0] = ls[0] * aA + src[1] * aB;
    ls[1] = ls[1] * aA + src[2] * aB;
#pragma unroll
    for (int u = 0; u < 2; u++)
#pragma unroll
      for (int dt = 0; dt < 5; dt++)
#pragma unroll
        for (int j = 0; j < 4; j++)
          o[u][dt][j] = o[u][dt][j] * aA + src[3 + u * 20 + dt * 4 + j] * aB;
  }
  __syncthreads();
  if (grp == 1) {
    float* dst = mb + (wq * 64 + l) * 42;
    dst[0] = ls[2]; dst[1] = ls[3];
#pragma unroll
    for (int u = 2; u < 4; u++)
#pragma unroll
      for (int dt = 0; dt < 5; dt++)
#pragma unroll
        for (int j = 0; j < 4; j++)
          dst[2 + (u - 2) * 20 + dt * 4 + j] = o[u][dt][j];
  }
  __syncthreads();
  if (grp == 0) {
    const float* src = mb + (wq * 64 + l) * 42;
    ls[2] = ls[2] * aA + src[0] * aB;
    ls[3] = ls[3] * aA + src[1] * aB;
#pragma unroll
    for (int u = 2; u < 4; u++)
#pragma unroll
      for (int dt = 0; dt < 5; dt++)
#pragma unroll
        for (int j = 0; j < 4; j++)
          o[u][dt][j] = o[u][dt][j] * aA + src[2 + (u - 2) * 20 + dt * 4 + j] * aB;

    // redistribute 1/rowsum (indexed by q=l&15) to o-rows (q'=4*(l>>4)+j)
#pragma unroll
    for (int u = 0; u < 4; u++) {
      const float inv = 1.0f / ls[u];
      float iv[4];
#pragma unroll
      for (int j = 0; j < 4; j++) {
        const int srcl = (l & 48) | ((l >> 4) * 4 + j);
        iv[j] = __shfl(inv, srcl);
      }
      const int orow = row0 + u * 16 + (l >> 4) * 4;
#pragma unroll
      for (int dt = 0; dt < 5; dt++)
#pragma unroll
        for (int j = 0; j < 4; j++)
          ao[(size_t)(orow + j) * HIDN + h * HD + dt * 16 + fr] = (f16)(o[u][dt][j] * iv[j]);
    }
  }
}

extern "C" void kernel_launch(void* const* d_in, const int* in_sizes, int n_in,
                              void* d_out, int out_size, void* d_ws, size_t ws_size,
                              hipStream_t stream) {
  const float* x      = (const float*)d_in[0];
  const int*   cu     = (const int*)d_in[1];
  const float* rpe    = (const float*)d_in[2];
  const float* qkv_w  = (const float*)d_in[3];
  const float* qkv_b  = (const float*)d_in[4];
  const float* proj_w = (const float*)d_in[5];
  const float* proj_b = (const float*)d_in[6];

  char* ws = (char*)d_ws;
  f16* xb    = (f16*)(ws);              // [4096][1280]
  f16* wqkv  = (f16*)(ws + 10485760);   // [3840][1280]
  f16* wproj = (f16*)(ws + 20316160);   // [1280][1280]
  f16* qkvb  = (f16*)(ws + 23592960);   // [4096][3840]
  f16* qh    = (f16*)(ws + 55050240);   // [16][4096][96]
  f16* kh    = (f16*)(ws + 67633152);   // [16][4096][96]
  f16* vt    = (f16*)(ws + 80216064);   // [16][80][4096] (kv-permuted)
  f16* ao    = xb;

  const int n0 = SEQ * HIDN, n1 = 3 * HIDN * HIDN, n2 = HIDN * HIDN;
  cvt3_kernel<<<(n0 + n1 + n2) / (256 * 8), 256, 0, stream>>>(
      x, qkv_w, proj_w, xb, wqkv, wproj, n0, n1, n2);

  qkv_gemm8<<<240, 512, 0, stream>>>(xb, wqkv, qkv_b, qkvb);

  prep_kernel<<<RPB + 1024, 256, 0, stream>>>(qkvb, rpe, qh, kh, vt);

  attn_kernel<<<256, 512, 0, stream>>>(qh, kh, vt, cu, ao);

  // proj: 320 blocks = 8 XCD x 40, nbx = 1280/128 = 10
  gemm_bt64<1><<<320, 256, 0, stream>>>(
      ao, wproj, proj_b, d_out, SEQ, HIDN, HIDN, 10, 40);
}